// Round 14
// baseline (698.694 us; speedup 1.0000x reference)
//
#include <hip/hip_runtime.h>
#include <hip/hip_fp16.h>
#include <math.h>

#define NN 50000
#define NE 800000

typedef _Float16 h8 __attribute__((ext_vector_type(8)));   // 4 VGPRs = MFMA A/B frag
typedef float    fv4 __attribute__((ext_vector_type(4)));  // MFMA C/D frag

static inline int cdiv(long a, int b){ return (int)((a + (long)b - 1) / b); }

// ---------------- degree count ----------------
__global__ void k_count(const int* __restrict__ dst, int* __restrict__ cnt, int E){
  int i = blockIdx.x*blockDim.x + threadIdx.x;
  if (i < E) atomicAdd(&cnt[dst[i]], 1);
}

// ---------------- exclusive scan (1 workgroup) + dinv ----------------
// off[i] = sum_{j<i} cnt[j]; cur = copy of off (scatter cursor); off[n] = E.
__global__ void __launch_bounds__(1024) k_scan(const int* __restrict__ cnt,
                                               int* __restrict__ off, int* __restrict__ cur,
                                               float* __restrict__ dinv, int n)
{
  __shared__ int ps[1024];
  const int tid = threadIdx.x;
  const int chunk = (n + 1023) / 1024;
  int b = tid * chunk;
  int e = min(b + chunk, n);
  int s = 0;
  for (int i = b; i < e; ++i) s += cnt[i];
  ps[tid] = s;
  __syncthreads();
  for (int d = 1; d < 1024; d <<= 1) {      // Hillis-Steele inclusive scan
    int v = (tid >= d) ? ps[tid - d] : 0;
    __syncthreads();
    ps[tid] += v;
    __syncthreads();
  }
  int run = (tid > 0) ? ps[tid - 1] : 0;
  for (int i = b; i < e; ++i) {
    int c = cnt[i];
    off[i] = run;
    cur[i] = run;
    dinv[i] = rsqrtf((float)c + 1.0f);      // +1 self loop
    run += c;
  }
  if (tid == 1023) off[n] = ps[1023];
}

// ---------------- dense CSR scatter: u16 sources, 1.6 MB (L2-resident) ------
__global__ void k_scatter(const int* __restrict__ ei, int* __restrict__ cur,
                          unsigned short* __restrict__ ssrc, int E){
  int i = blockIdx.x*blockDim.x + threadIdx.x;
  if (i >= E) return;
  int s = ei[i];
  int d = ei[E + i];
  int p = atomicAdd(&cur[d], 1);
  ssrc[p] = (unsigned short)s;
}

// ---------------- weight prep: fp16 [n][k] images (B-operand layout) ----------
__global__ void k_trh(const float* __restrict__ W1, const float* __restrict__ W2,
                      const float* __restrict__ wih, const float* __restrict__ l1,
                      const float* __restrict__ l2,  const float* __restrict__ l3,
                      _Float16* __restrict__ w1t, _Float16* __restrict__ w2t,
                      _Float16* __restrict__ wihh, _Float16* __restrict__ l1h,
                      _Float16* __restrict__ l2h, float* __restrict__ l3f)
{
  int i = blockIdx.x*blockDim.x + threadIdx.x;
  if (i < 14336) { int n=i>>7, k=i&127; w1t[i] = (_Float16)((n<100&&k<100)? W1[k*100+n] : 0.f); return; }
  i -= 14336;
  if (i < 14336) { int n=i>>7, k=i&127; w2t[i] = (_Float16)((n<100&&k<100)? W2[k*100+n] : 0.f); return; }
  i -= 14336;
  if (i < 8192)  { int n=i>>7, k=i&127; wihh[i] = (_Float16)((n<50&&k<100)? wih[n*100+k] : 0.f); return; }
  i -= 8192;
  if (i < 4096)  { int n=i>>6, k=i&63;  l1h[i] = (_Float16)((n<50&&k<50)? l1[n*50+k] : 0.f); return; }
  i -= 4096;
  if (i < 2048)  { int n=i>>6, k=i&63;  l2h[i] = (_Float16)((n<30&&k<50)? l2[n*50+k] : 0.f); return; }
  i -= 2048;
  if (i < 960)   { int k=i>>5, c=i&31;  l3f[i] = (c<30)? l3[c*30+k] : 0.f; return; }
}

// ---------------- GCN aggregation over dense CSR, fp16 rows --------------
// out[d][c] = bias[c] + dinv[d]*( xws[d][c] + sum_{i in [off[d],off[d+1])} xws[ssrc[i]][c] )
__global__ void k_gather(const __half* __restrict__ xws, const unsigned short* __restrict__ ssrc,
                         const int* __restrict__ off, const float* __restrict__ dinv,
                         const float* __restrict__ bias, float* __restrict__ out)
{
  int d = blockIdx.x;
  int c = threadIdx.x;
  if (c >= 100) return;
  int b = off[d], e = off[d+1];
  float a0 = __half2float(xws[(long)d*100 + c]);   // self-loop term
  float a1 = 0.f, a2 = 0.f, a3 = 0.f;
  int i = b;
  for (; i + 4 <= e; i += 4) {
    int s0 = ssrc[i], s1 = ssrc[i+1], s2 = ssrc[i+2], s3 = ssrc[i+3];  // wave-uniform
    a0 += __half2float(xws[(long)s0*100 + c]);     // coalesced 200B row reads
    a1 += __half2float(xws[(long)s1*100 + c]);
    a2 += __half2float(xws[(long)s2*100 + c]);
    a3 += __half2float(xws[(long)s3*100 + c]);
  }
  for (; i < e; ++i) a0 += __half2float(xws[(long)ssrc[i]*100 + c]);
  float acc = (a0 + a1) + (a2 + a3);
  out[(long)d*100 + c] = fmaf(dinv[d], acc, bias[c]);
}

// ---------------- MFMA GEMM: out[r][c] = A'[r][:] @ Wt[c][:] ----------------
// 256 thr = 4 waves; block = 64 rows. BN-in scale/shift computed from raw
// sums in an LDS preamble (bn_fin folded in). A fp32 -> fp16 LDS, K padded to
// 32*KS. a_frag A[m=lane&15][k=q*8+j]; b_frag from fp16 Wt[n][k] (L1-hot);
// D: col=lane&15, row=q*4+reg.
template<int KO,int KS,int NT,int CO,int BNIN,int RELUIN,int NB,int OUTH>
__global__ void __launch_bounds__(256) k_mfma(
    const float* __restrict__ A, const _Float16* __restrict__ Wt,
    const float* __restrict__ bias1, const float* __restrict__ bias2,
    const float* __restrict__ sums, const float* __restrict__ sqs,
    const float* __restrict__ gw, const float* __restrict__ be,
    const float* __restrict__ dinv, void* __restrict__ outv, int rows, float invN)
{
  constexpr int KP  = KS*32;
  constexpr int LDA = KP + 8;
  __shared__ _Float16 Ah[64 * LDA];
  __shared__ float scS[BNIN ? KO : 1], shS[BNIN ? KO : 1];
  const int tid = threadIdx.x;
  const int r0  = blockIdx.x * 64;

  if (BNIN) {                      // folded BN-finalize (per block, tiny)
    for (int c = tid; c < KO; c += 256) {
      float m = sums[c]*invN;
      float v = fmaxf(sqs[c]*invN - m*m, 0.f);
      float s = gw[c]*rsqrtf(v + 1e-5f);
      scS[c] = s;
      shS[c] = be[c] - m*s;
    }
    __syncthreads();
  }

  for (int e = tid; e < 64*(KO/2); e += 256) {
    int rr = e / (KO/2);
    int kk = (e - rr*(KO/2)) * 2;
    int gr = r0 + rr;
    float v0 = 0.f, v1 = 0.f;
    if (gr < rows) {
      float2 t = *(const float2*)(A + (long)gr*KO + kk);
      v0 = t.x; v1 = t.y;
      if (BNIN) {
        v0 = fmaf(v0, scS[kk],   shS[kk]);   if (RELUIN) v0 = fmaxf(v0, 0.f);
        v1 = fmaf(v1, scS[kk+1], shS[kk+1]); if (RELUIN) v1 = fmaxf(v1, 0.f);
      }
    }
    Ah[rr*LDA + kk]     = (_Float16)v0;
    Ah[rr*LDA + kk + 1] = (_Float16)v1;
  }
  if (KP > KO) {
    for (int e = tid; e < 64*(KP-KO); e += 256) {
      int rr = e / (KP-KO), kk = KO + (e - rr*(KP-KO));
      Ah[rr*LDA + kk] = (_Float16)0.f;
    }
  }
  __syncthreads();

  const int wave = tid >> 6, lane = tid & 63;
  const int m = lane & 15, q = lane >> 4;
  const int row = wave*16 + m;
  h8 af[KS];
  #pragma unroll
  for (int ks = 0; ks < KS; ++ks)
    af[ks] = *(const h8*)(Ah + row*LDA + ks*32 + q*8);

  const int grb = r0 + wave*16 + q*4;
  #pragma unroll
  for (int nt = 0; nt < NT; ++nt) {
    fv4 acc = {0.f, 0.f, 0.f, 0.f};
    #pragma unroll
    for (int ks = 0; ks < KS; ++ks) {
      h8 bf = *(const h8*)(Wt + (long)(nt*16 + m)*KP + ks*32 + q*8);
      acc = __builtin_amdgcn_mfma_f32_16x16x32_f16(af[ks], bf, acc, 0, 0, 0);
    }
    int c = nt*16 + m;
    if (c < CO) {
      float bi = 0.f;
      if (NB >= 1) bi = bias1[c];
      if (NB == 2) bi += bias2[c];
      #pragma unroll
      for (int i = 0; i < 4; ++i) {
        int gr = grb + i;
        if (gr < rows) {
          if (OUTH) ((__half*)outv)[(long)gr*CO + c] = __float2half(acc[i] * dinv[gr]);
          else      ((float*)outv)[(long)gr*CO + c] = acc[i] + bi;
        }
      }
    }
  }
}

// ---------------- all-LDS VALU GEMM + log_softmax (lin3 only) ----------------
// BN-in finalize folded in (sums4 raw).
template<int K, int C, int WC, int CT>
__global__ void __launch_bounds__(64) k_tgemm_lsm(
    const float* __restrict__ A, const float* __restrict__ W,
    const float* __restrict__ bias1,
    const float* __restrict__ sums, const float* __restrict__ sqs,
    const float* __restrict__ gw, const float* __restrict__ be,
    float* __restrict__ out, int rows, float invN)
{
  constexpr int TM  = 64;
  constexpr int LDK = K + 1;
  __shared__ __align__(16) float As[TM * LDK];
  __shared__ __align__(16) float Ws[K * WC + 16];
  __shared__ float scS[K], shS[K];
  const int tid = threadIdx.x;
  const int r0  = blockIdx.x * TM;

  if (tid < K) {
    float m = sums[tid]*invN;
    float v = fmaxf(sqs[tid]*invN - m*m, 0.f);
    float s = gw[tid]*rsqrtf(v + 1e-5f);
    scS[tid] = s;
    shS[tid] = be[tid] - m*s;
  }
  __syncthreads();

  for (int e = tid; e < K*WC/4; e += TM) {
    float4 t = *(const float4*)(W + 4*e);
    *(float4*)(Ws + 4*e) = t;
  }
  for (int e = tid; e < TM*K/2; e += TM) {
    int idx = e * 2;
    int rr  = idx / K;
    int kk  = idx - rr*K;
    int gr  = r0 + rr;
    float v0 = 0.f, v1 = 0.f;
    if (gr < rows) {
      float2 t = *(const float2*)(A + (long)gr*K + kk);
      v0 = fmaxf(fmaf(t.x, scS[kk],   shS[kk]),   0.f);
      v1 = fmaxf(fmaf(t.y, scS[kk+1], shS[kk+1]), 0.f);
    }
    As[rr*LDK + kk] = v0;
    As[rr*LDK + kk + 1] = v1;
  }
  __syncthreads();

  const int r = tid;
  float acc[CT];
  #pragma unroll
  for (int j = 0; j < CT; ++j) acc[j] = (j < C) ? bias1[j] : 0.f;
  #pragma unroll 2
  for (int k = 0; k < K; ++k) {
    float a = As[r*LDK + k];
    const float* p = Ws + k*WC;
    #pragma unroll
    for (int qd = 0; qd < CT/4; ++qd) {
      float4 t = *(const float4*)(p + 4*qd);
      acc[4*qd+0] = fmaf(a, t.x, acc[4*qd+0]);
      acc[4*qd+1] = fmaf(a, t.y, acc[4*qd+1]);
      acc[4*qd+2] = fmaf(a, t.z, acc[4*qd+2]);
      acc[4*qd+3] = fmaf(a, t.w, acc[4*qd+3]);
    }
  }
  int gr = r0 + r;
  if (gr >= rows) return;
  float mx = acc[0];
  #pragma unroll
  for (int j = 1; j < C; ++j) mx = fmaxf(mx, acc[j]);
  float s = 0.0f;
  #pragma unroll
  for (int j = 0; j < C; ++j) s += expf(acc[j] - mx);
  float l = mx + logf(s);
  float* o = out + (long)gr*C;
  #pragma unroll
  for (int j = 0; j < C; ++j) o[j] = acc[j] - l;
}

// ---------------- BatchNorm stats (one pass) ----------------
__global__ void k_bn_stats(const float* __restrict__ x, float* __restrict__ sums,
                           float* __restrict__ sqs, int rows, int C)
{
  int c = threadIdx.x;
  if (c >= C) return;
  float s = 0.0f, q = 0.0f;
  for (int r = blockIdx.x; r < rows; r += gridDim.x) {
    float v = x[(long)r*C + c];
    s += v;
    q = fmaf(v, v, q);
  }
  atomicAdd(&sums[c], s);
  atomicAdd(&sqs[c], q);
}

// ---------------- fast tanh ----------------
__device__ __forceinline__ float fast_tanh(float z){
  float az = fabsf(z);
  float e  = __expf(2.0f*az);
  float t  = 1.0f - 2.0f*__builtin_amdgcn_rcpf(e + 1.0f);
  return copysignf(t, z);
}

__device__ __forceinline__ float rlane(float v, int l){
  return __uint_as_float(__builtin_amdgcn_readlane(__float_as_uint(v), l));
}

// ---------------- parallel-chunk RNN ----------------
// Whh kept live in VGPRs via opaque `one` multiply (anti-remat, R13-verified).
__global__ void __launch_bounds__(64,1) k_rnn_par(const float* __restrict__ u,
                                                  const float* __restrict__ Whh,
                                                  float* __restrict__ ys,
                                                  int N, int L, int W)
{
  const int lane = threadIdx.x;
  const int li = min(lane, 49);          // lanes 50-63 mirror row 49, never store
  const int t0 = blockIdx.x * L;
  if (t0 >= N) return;
  const int t1 = min(t0 + L, N);
  const int ts = max(0, t0 - W);

  float one;
  asm volatile("v_mov_b32 %0, 1.0" : "=v"(one));
  float w[50];
  #pragma unroll
  for (int j = 0; j < 50; ++j) w[j] = Whh[li*50 + j] * one;   // non-remat-able

  const float* up = u + (long)ts*50 + li;
  float r0 = up[0];
  float r1 = up[50];
  up += 100;

  float h = 0.0f;

#define RNN_STEP(STORE)                                         \
  {                                                             \
    float ucur = r0; r0 = r1; r1 = up[0]; up += 50;             \
    float a0 = 0.f, a1 = 0.f, a2 = 0.f, a3 = 0.f;               \
    _Pragma("unroll")                                           \
    for (int j = 0; j < 48; j += 4) {                           \
      a0 = fmaf(w[j+0], rlane(h, j+0), a0);                     \
      a1 = fmaf(w[j+1], rlane(h, j+1), a1);                     \
      a2 = fmaf(w[j+2], rlane(h, j+2), a2);                     \
      a3 = fmaf(w[j+3], rlane(h, j+3), a3);                     \
    }                                                           \
    a0 = fmaf(w[48], rlane(h, 48), a0);                         \
    a1 = fmaf(w[49], rlane(h, 49), a1);                         \
    h = fast_tanh(ucur + (a0 + a1) + (a2 + a3));                \
    if (STORE && lane < 50) ys[(long)t*50 + lane] = h;          \
  }

  for (int t = ts; t < t0; ++t) RNN_STEP(0)   // warmup: no stores
  for (int t = t0; t < t1; ++t) RNN_STEP(1)   // output window
#undef RNN_STEP
}

// ---------------- launch ----------------
extern "C" void kernel_launch(void* const* d_in, const int* in_sizes, int n_in,
                              void* d_out, int out_size, void* d_ws, size_t ws_size,
                              hipStream_t stream)
{
  const float* x   = (const float*)d_in[0];
  const int*   ei  = (const int*)  d_in[1];
  const float* W1  = (const float*)d_in[2];
  const float* b1  = (const float*)d_in[3];
  const float* W2  = (const float*)d_in[4];
  const float* b2  = (const float*)d_in[5];
  const float* g1  = (const float*)d_in[6];
  const float* be1 = (const float*)d_in[7];
  const float* g2  = (const float*)d_in[8];
  const float* be2 = (const float*)d_in[9];
  const float* g3  = (const float*)d_in[10];
  const float* be3 = (const float*)d_in[11];
  const float* g4  = (const float*)d_in[12];
  const float* be4 = (const float*)d_in[13];
  const float* Wih = (const float*)d_in[14];
  const float* Whh = (const float*)d_in[15];
  const float* bih = (const float*)d_in[16];
  const float* bhh = (const float*)d_in[17];
  const float* lw1 = (const float*)d_in[18];
  const float* lb1 = (const float*)d_in[19];
  const float* lw2 = (const float*)d_in[20];
  const float* lb2 = (const float*)d_in[21];
  const float* lw3 = (const float*)d_in[22];
  const float* lb3 = (const float*)d_in[23];
  float* out = (float*)d_out;

  // workspace layout (floats) -- st and cnt adjacent so one memset zeroes both
  float* bufA = (float*)d_ws;            // 5,000,000
  float* bufB = bufA + 5000000;          // 5,000,000
  float* bufC = bufB + 5000000;          // 5,000,000
  float* st   = bufC + 5000000;          // 8 x 128 stats (sums/sqs x4)
  int*   cnt  = (int*)(st + 8*128);      // 50,000   <- zeroed with st
  int*   cur  = cnt + NN;                // 50,000 (seeded by k_scan)
  int*   off  = cur + NN;                // 50,001
  float* dinv = (float*)(off + NN + 1);  // 50,000
  unsigned short* ssrc = (unsigned short*)(dinv + NN);  // 800,000 u16 = 1.6 MB
  _Float16* wh = (_Float16*)(ssrc + NE); // fp16 weight images
  _Float16* w1t  = wh;            // [112][128]
  _Float16* w2t  = wh + 14336;    // [112][128]
  _Float16* wihh = wh + 28672;    // [64][128]
  _Float16* l1h  = wh + 36864;    // [64][64]
  _Float16* l2h  = wh + 40960;    // [32][64]
  float*    l3f  = (float*)(wh + 43008); // [30][32] fp32

  __half* xwh = (__half*)bufA;           // 5M halves = 10 MB staging (inside bufA)

  float* sums1 = st + 0*128; float* sqs1 = st + 1*128;
  float* sums2 = st + 2*128; float* sqs2 = st + 3*128;
  float* sums3 = st + 4*128; float* sqs3 = st + 5*128;
  float* sums4 = st + 6*128; float* sqs4 = st + 7*128;

  const int B = 256;
  const float invN = 1.0f / (float)NN;
  const int statsGrid = 784;
  const int gt = cdiv(NN, 64);           // 782 tile-blocks

  // zero stats + cnt in one shot (adjacent)
  hipMemsetAsync(st, 0, 8*128*sizeof(float) + NN*sizeof(int), stream);

  // ---- weight prep + dense-CSR build ----
  k_trh<<<cdiv(43968,B), B, 0, stream>>>(W1, W2, Wih, lw1, lw2, lw3,
                                         w1t, w2t, wihh, l1h, l2h, l3f);
  k_count<<<cdiv(NE,B), B, 0, stream>>>(ei + NE, cnt, NE);
  k_scan<<<1, 1024, 0, stream>>>(cnt, off, cur, dinv, NN);
  k_scatter<<<cdiv(NE,B), B, 0, stream>>>(ei, cur, ssrc, NE);

  // ---- GCN conv 1: xws = (x @ W1)*dinv (fp16, MFMA) ; aggregate (+b1) ----
  k_mfma<100,4,7,100,0,0,0,1><<<gt, 256, 0, stream>>>(x, w1t, nullptr, nullptr,
      nullptr, nullptr, nullptr, nullptr, dinv, xwh, NN, invN);
  k_gather<<<NN, 128, 0, stream>>>(xwh, ssrc, off, dinv, b1, bufB);
  k_bn_stats<<<statsGrid, 128, 0, stream>>>(bufB, sums1, sqs1, NN, 100);

  // ---- GCN conv 2: xws = (relu(BN1(h1)) @ W2)*dinv (MFMA) ; aggregate (+b2) ----
  k_mfma<100,4,7,100,1,1,0,1><<<gt, 256, 0, stream>>>(bufB, w2t, nullptr, nullptr,
      sums1, sqs1, g1, be1, dinv, xwh, NN, invN);
  k_gather<<<NN, 128, 0, stream>>>(xwh, ssrc, off, dinv, b2, bufC);
  k_bn_stats<<<statsGrid, 128, 0, stream>>>(bufC, sums2, sqs2, NN, 100);

  // ---- u = BN2(h2) @ Wih^T + bih + bhh (MFMA) ; parallel-chunk RNN ----
  k_mfma<100,4,4,50,1,0,2,0><<<gt, 256, 0, stream>>>(bufC, wihh, bih, bhh,
      sums2, sqs2, g2, be2, nullptr, bufA, NN, invN);
  {
    const int L = 32, W = 48;
    k_rnn_par<<<cdiv(NN,L), 64, 0, stream>>>(bufA, Whh, bufB, NN, L, W);
  }

  // ---- Linear1 (MFMA) ----
  k_mfma<50,2,4,50,0,0,1,0><<<gt, 256, 0, stream>>>(bufB, l1h, lb1, nullptr,
      nullptr, nullptr, nullptr, nullptr, nullptr, bufC, NN, invN);
  k_bn_stats<<<statsGrid, 64, 0, stream>>>(bufC, sums3, sqs3, NN, 50);

  // ---- Linear2 (BN3+relu in, MFMA) ----
  k_mfma<50,2,2,30,1,1,1,0><<<gt, 256, 0, stream>>>(bufC, l2h, lb2, nullptr,
      sums3, sqs3, g3, be3, nullptr, bufA, NN, invN);
  k_bn_stats<<<statsGrid, 64, 0, stream>>>(bufA, sums4, sqs4, NN, 30);

  // ---- Linear3 (BN4+relu in) + log_softmax ----
  k_tgemm_lsm<30,30,32,32><<<gt, 64, 0, stream>>>(bufA, l3f, lb3,
      sums4, sqs4, g4, be4, out, NN, invN);
}

// Round 15
// 587.033 us; speedup vs baseline: 1.1902x; 1.1902x over previous
//
#include <hip/hip_runtime.h>
#include <hip/hip_fp16.h>
#include <math.h>

#define NN 50000
#define NE 800000

typedef _Float16 h8 __attribute__((ext_vector_type(8)));   // 4 VGPRs = MFMA A/B frag
typedef float    fv4 __attribute__((ext_vector_type(4)));  // MFMA C/D frag

static inline int cdiv(long a, int b){ return (int)((a + (long)b - 1) / b); }

// ---------------- degree count ----------------
__global__ void k_count(const int* __restrict__ dst, int* __restrict__ cnt, int E){
  int i = blockIdx.x*blockDim.x + threadIdx.x;
  if (i < E) atomicAdd(&cnt[dst[i]], 1);
}

// ---------------- two-level parallel scan (R14's 1-WG serial scan was 136us) --
// phase 1: per-64-chunk sums (coalesced + wave reduce)
__global__ void __launch_bounds__(64) k_part(const int* __restrict__ cnt,
                                             int* __restrict__ part, int n)
{
  int i = blockIdx.x*64 + threadIdx.x;
  int s = (i < n) ? cnt[i] : 0;
  #pragma unroll
  for (int d = 32; d > 0; d >>= 1) s += __shfl_down(s, d);
  if (threadIdx.x == 0) part[blockIdx.x] = s;
}

// phase 2: scan the block partials (<=1024) in one workgroup
__global__ void __launch_bounds__(1024) k_scan1(const int* __restrict__ part,
                                                int* __restrict__ bbase, int nb)
{
  __shared__ int ps[1024];
  int tid = threadIdx.x;
  int v = (tid < nb) ? part[tid] : 0;
  ps[tid] = v;
  __syncthreads();
  for (int d = 1; d < 1024; d <<= 1) {
    int t = (tid >= d) ? ps[tid - d] : 0;
    __syncthreads();
    ps[tid] += t;
    __syncthreads();
  }
  if (tid < nb) bbase[tid] = ps[tid] - v;   // exclusive base
}

// phase 3: per-chunk exclusive prefix + base -> off/cur/dinv
__global__ void __launch_bounds__(64) k_off(const int* __restrict__ cnt,
                                            const int* __restrict__ bbase,
                                            int* __restrict__ off, int* __restrict__ cur,
                                            float* __restrict__ dinv, int n, int E)
{
  int lane = threadIdx.x;
  int i = blockIdx.x*64 + lane;
  int c = (i < n) ? cnt[i] : 0;
  int incl = c;
  #pragma unroll
  for (int d = 1; d < 64; d <<= 1) {
    int t = __shfl_up(incl, d);
    if (lane >= d) incl += t;
  }
  int base = bbase[blockIdx.x];
  if (i < n) {
    int o = base + incl - c;     // exclusive
    off[i] = o;
    cur[i] = o;
    dinv[i] = rsqrtf((float)c + 1.0f);   // +1 self loop
    if (i == n - 1) off[n] = E;
  }
}

// ---------------- dense CSR scatter: u16 sources, 1.6 MB (L2-resident) ------
__global__ void k_scatter(const int* __restrict__ ei, int* __restrict__ cur,
                          unsigned short* __restrict__ ssrc, int E){
  int i = blockIdx.x*blockDim.x + threadIdx.x;
  if (i >= E) return;
  int s = ei[i];
  int d = ei[E + i];
  int p = atomicAdd(&cur[d], 1);
  ssrc[p] = (unsigned short)s;
}

// ---------------- weight prep: fp16 [n][k] images (B-operand layout) ----------
__global__ void k_trh(const float* __restrict__ W1, const float* __restrict__ W2,
                      const float* __restrict__ wih, const float* __restrict__ l1,
                      const float* __restrict__ l2,  const float* __restrict__ l3,
                      _Float16* __restrict__ w1t, _Float16* __restrict__ w2t,
                      _Float16* __restrict__ wihh, _Float16* __restrict__ l1h,
                      _Float16* __restrict__ l2h, float* __restrict__ l3f)
{
  int i = blockIdx.x*blockDim.x + threadIdx.x;
  if (i < 14336) { int n=i>>7, k=i&127; w1t[i] = (_Float16)((n<100&&k<100)? W1[k*100+n] : 0.f); return; }
  i -= 14336;
  if (i < 14336) { int n=i>>7, k=i&127; w2t[i] = (_Float16)((n<100&&k<100)? W2[k*100+n] : 0.f); return; }
  i -= 14336;
  if (i < 8192)  { int n=i>>7, k=i&127; wihh[i] = (_Float16)((n<50&&k<100)? wih[n*100+k] : 0.f); return; }
  i -= 8192;
  if (i < 4096)  { int n=i>>6, k=i&63;  l1h[i] = (_Float16)((n<50&&k<50)? l1[n*50+k] : 0.f); return; }
  i -= 4096;
  if (i < 2048)  { int n=i>>6, k=i&63;  l2h[i] = (_Float16)((n<30&&k<50)? l2[n*50+k] : 0.f); return; }
  i -= 2048;
  if (i < 960)   { int k=i>>5, c=i&31;  l3f[i] = (c<30)? l3[c*30+k] : 0.f; return; }
}

// ---------------- GCN aggregation over dense CSR, fp16 rows --------------
__global__ void k_gather(const __half* __restrict__ xws, const unsigned short* __restrict__ ssrc,
                         const int* __restrict__ off, const float* __restrict__ dinv,
                         const float* __restrict__ bias, float* __restrict__ out)
{
  int d = blockIdx.x;
  int c = threadIdx.x;
  if (c >= 100) return;
  int b = off[d], e = off[d+1];
  float a0 = __half2float(xws[(long)d*100 + c]);   // self-loop term
  float a1 = 0.f, a2 = 0.f, a3 = 0.f;
  int i = b;
  for (; i + 4 <= e; i += 4) {
    int s0 = ssrc[i], s1 = ssrc[i+1], s2 = ssrc[i+2], s3 = ssrc[i+3];  // wave-uniform
    a0 += __half2float(xws[(long)s0*100 + c]);     // coalesced 200B row reads
    a1 += __half2float(xws[(long)s1*100 + c]);
    a2 += __half2float(xws[(long)s2*100 + c]);
    a3 += __half2float(xws[(long)s3*100 + c]);
  }
  for (; i < e; ++i) a0 += __half2float(xws[(long)ssrc[i]*100 + c]);
  float acc = (a0 + a1) + (a2 + a3);
  out[(long)d*100 + c] = fmaf(dinv[d], acc, bias[c]);
}

// ---------------- MFMA GEMM: out[r][c] = A'[r][:] @ Wt[c][:] ----------------
template<int KO,int KS,int NT,int CO,int BNIN,int RELUIN,int NB,int OUTH>
__global__ void __launch_bounds__(256) k_mfma(
    const float* __restrict__ A, const _Float16* __restrict__ Wt,
    const float* __restrict__ bias1, const float* __restrict__ bias2,
    const float* __restrict__ sums, const float* __restrict__ sqs,
    const float* __restrict__ gw, const float* __restrict__ be,
    const float* __restrict__ dinv, void* __restrict__ outv, int rows, float invN)
{
  constexpr int KP  = KS*32;
  constexpr int LDA = KP + 8;
  __shared__ _Float16 Ah[64 * LDA];
  __shared__ float scS[BNIN ? KO : 1], shS[BNIN ? KO : 1];
  const int tid = threadIdx.x;
  const int r0  = blockIdx.x * 64;

  if (BNIN) {                      // folded BN-finalize (per block, tiny)
    for (int c = tid; c < KO; c += 256) {
      float m = sums[c]*invN;
      float v = fmaxf(sqs[c]*invN - m*m, 0.f);
      float s = gw[c]*rsqrtf(v + 1e-5f);
      scS[c] = s;
      shS[c] = be[c] - m*s;
    }
    __syncthreads();
  }

  for (int e = tid; e < 64*(KO/2); e += 256) {
    int rr = e / (KO/2);
    int kk = (e - rr*(KO/2)) * 2;
    int gr = r0 + rr;
    float v0 = 0.f, v1 = 0.f;
    if (gr < rows) {
      float2 t = *(const float2*)(A + (long)gr*KO + kk);
      v0 = t.x; v1 = t.y;
      if (BNIN) {
        v0 = fmaf(v0, scS[kk],   shS[kk]);   if (RELUIN) v0 = fmaxf(v0, 0.f);
        v1 = fmaf(v1, scS[kk+1], shS[kk+1]); if (RELUIN) v1 = fmaxf(v1, 0.f);
      }
    }
    Ah[rr*LDA + kk]     = (_Float16)v0;
    Ah[rr*LDA + kk + 1] = (_Float16)v1;
  }
  if (KP > KO) {
    for (int e = tid; e < 64*(KP-KO); e += 256) {
      int rr = e / (KP-KO), kk = KO + (e - rr*(KP-KO));
      Ah[rr*LDA + kk] = (_Float16)0.f;
    }
  }
  __syncthreads();

  const int wave = tid >> 6, lane = tid & 63;
  const int m = lane & 15, q = lane >> 4;
  const int row = wave*16 + m;
  h8 af[KS];
  #pragma unroll
  for (int ks = 0; ks < KS; ++ks)
    af[ks] = *(const h8*)(Ah + row*LDA + ks*32 + q*8);

  const int grb = r0 + wave*16 + q*4;
  #pragma unroll
  for (int nt = 0; nt < NT; ++nt) {
    fv4 acc = {0.f, 0.f, 0.f, 0.f};
    #pragma unroll
    for (int ks = 0; ks < KS; ++ks) {
      h8 bf = *(const h8*)(Wt + (long)(nt*16 + m)*KP + ks*32 + q*8);
      acc = __builtin_amdgcn_mfma_f32_16x16x32_f16(af[ks], bf, acc, 0, 0, 0);
    }
    int c = nt*16 + m;
    if (c < CO) {
      float bi = 0.f;
      if (NB >= 1) bi = bias1[c];
      if (NB == 2) bi += bias2[c];
      #pragma unroll
      for (int i = 0; i < 4; ++i) {
        int gr = grb + i;
        if (gr < rows) {
          if (OUTH) ((__half*)outv)[(long)gr*CO + c] = __float2half(acc[i] * dinv[gr]);
          else      ((float*)outv)[(long)gr*CO + c] = acc[i] + bi;
        }
      }
    }
  }
}

// ---------------- all-LDS VALU GEMM + log_softmax (lin3 only) ----------------
template<int K, int C, int WC, int CT>
__global__ void __launch_bounds__(64) k_tgemm_lsm(
    const float* __restrict__ A, const float* __restrict__ W,
    const float* __restrict__ bias1,
    const float* __restrict__ sums, const float* __restrict__ sqs,
    const float* __restrict__ gw, const float* __restrict__ be,
    float* __restrict__ out, int rows, float invN)
{
  constexpr int TM  = 64;
  constexpr int LDK = K + 1;
  __shared__ __align__(16) float As[TM * LDK];
  __shared__ __align__(16) float Ws[K * WC + 16];
  __shared__ float scS[K], shS[K];
  const int tid = threadIdx.x;
  const int r0  = blockIdx.x * TM;

  if (tid < K) {
    float m = sums[tid]*invN;
    float v = fmaxf(sqs[tid]*invN - m*m, 0.f);
    float s = gw[tid]*rsqrtf(v + 1e-5f);
    scS[tid] = s;
    shS[tid] = be[tid] - m*s;
  }
  __syncthreads();

  for (int e = tid; e < K*WC/4; e += TM) {
    float4 t = *(const float4*)(W + 4*e);
    *(float4*)(Ws + 4*e) = t;
  }
  for (int e = tid; e < TM*K/2; e += TM) {
    int idx = e * 2;
    int rr  = idx / K;
    int kk  = idx - rr*K;
    int gr  = r0 + rr;
    float v0 = 0.f, v1 = 0.f;
    if (gr < rows) {
      float2 t = *(const float2*)(A + (long)gr*K + kk);
      v0 = fmaxf(fmaf(t.x, scS[kk],   shS[kk]),   0.f);
      v1 = fmaxf(fmaf(t.y, scS[kk+1], shS[kk+1]), 0.f);
    }
    As[rr*LDK + kk] = v0;
    As[rr*LDK + kk + 1] = v1;
  }
  __syncthreads();

  const int r = tid;
  float acc[CT];
  #pragma unroll
  for (int j = 0; j < CT; ++j) acc[j] = (j < C) ? bias1[j] : 0.f;
  #pragma unroll 2
  for (int k = 0; k < K; ++k) {
    float a = As[r*LDK + k];
    const float* p = Ws + k*WC;
    #pragma unroll
    for (int qd = 0; qd < CT/4; ++qd) {
      float4 t = *(const float4*)(p + 4*qd);
      acc[4*qd+0] = fmaf(a, t.x, acc[4*qd+0]);
      acc[4*qd+1] = fmaf(a, t.y, acc[4*qd+1]);
      acc[4*qd+2] = fmaf(a, t.z, acc[4*qd+2]);
      acc[4*qd+3] = fmaf(a, t.w, acc[4*qd+3]);
    }
  }
  int gr = r0 + r;
  if (gr >= rows) return;
  float mx = acc[0];
  #pragma unroll
  for (int j = 1; j < C; ++j) mx = fmaxf(mx, acc[j]);
  float s = 0.0f;
  #pragma unroll
  for (int j = 0; j < C; ++j) s += expf(acc[j] - mx);
  float l = mx + logf(s);
  float* o = out + (long)gr*C;
  #pragma unroll
  for (int j = 0; j < C; ++j) o[j] = acc[j] - l;
}

// ---------------- BatchNorm stats (one pass) ----------------
__global__ void k_bn_stats(const float* __restrict__ x, float* __restrict__ sums,
                           float* __restrict__ sqs, int rows, int C)
{
  int c = threadIdx.x;
  if (c >= C) return;
  float s = 0.0f, q = 0.0f;
  for (int r = blockIdx.x; r < rows; r += gridDim.x) {
    float v = x[(long)r*C + c];
    s += v;
    q = fmaf(v, v, q);
  }
  atomicAdd(&sums[c], s);
  atomicAdd(&sqs[c], q);
}

// ---------------- fast tanh ----------------
__device__ __forceinline__ float fast_tanh(float z){
  float az = fabsf(z);
  float e  = __expf(2.0f*az);
  float t  = 1.0f - 2.0f*__builtin_amdgcn_rcpf(e + 1.0f);
  return copysignf(t, z);
}

__device__ __forceinline__ float rlane(float v, int l){
  return __uint_as_float(__builtin_amdgcn_readlane(__float_as_uint(v), l));
}

// ---------------- parallel-chunk RNN ----------------
// Whh kept live in VGPRs via opaque `one` multiply (anti-remat, R13-verified).
__global__ void __launch_bounds__(64,1) k_rnn_par(const float* __restrict__ u,
                                                  const float* __restrict__ Whh,
                                                  float* __restrict__ ys,
                                                  int N, int L, int W)
{
  const int lane = threadIdx.x;
  const int li = min(lane, 49);          // lanes 50-63 mirror row 49, never store
  const int t0 = blockIdx.x * L;
  if (t0 >= N) return;
  const int t1 = min(t0 + L, N);
  const int ts = max(0, t0 - W);

  float one;
  asm volatile("v_mov_b32 %0, 1.0" : "=v"(one));
  float w[50];
  #pragma unroll
  for (int j = 0; j < 50; ++j) w[j] = Whh[li*50 + j] * one;   // non-remat-able

  const float* up = u + (long)ts*50 + li;
  float r0 = up[0];
  float r1 = up[50];
  up += 100;

  float h = 0.0f;

#define RNN_STEP(STORE)                                         \
  {                                                             \
    float ucur = r0; r0 = r1; r1 = up[0]; up += 50;             \
    float a0 = 0.f, a1 = 0.f, a2 = 0.f, a3 = 0.f;               \
    _Pragma("unroll")                                           \
    for (int j = 0; j < 48; j += 4) {                           \
      a0 = fmaf(w[j+0], rlane(h, j+0), a0);                     \
      a1 = fmaf(w[j+1], rlane(h, j+1), a1);                     \
      a2 = fmaf(w[j+2], rlane(h, j+2), a2);                     \
      a3 = fmaf(w[j+3], rlane(h, j+3), a3);                     \
    }                                                           \
    a0 = fmaf(w[48], rlane(h, 48), a0);                         \
    a1 = fmaf(w[49], rlane(h, 49), a1);                         \
    h = fast_tanh(ucur + (a0 + a1) + (a2 + a3));                \
    if (STORE && lane < 50) ys[(long)t*50 + lane] = h;          \
  }

  for (int t = ts; t < t0; ++t) RNN_STEP(0)   // warmup: no stores
  for (int t = t0; t < t1; ++t) RNN_STEP(1)   // output window
#undef RNN_STEP
}

// ---------------- launch ----------------
extern "C" void kernel_launch(void* const* d_in, const int* in_sizes, int n_in,
                              void* d_out, int out_size, void* d_ws, size_t ws_size,
                              hipStream_t stream)
{
  const float* x   = (const float*)d_in[0];
  const int*   ei  = (const int*)  d_in[1];
  const float* W1  = (const float*)d_in[2];
  const float* b1  = (const float*)d_in[3];
  const float* W2  = (const float*)d_in[4];
  const float* b2  = (const float*)d_in[5];
  const float* g1  = (const float*)d_in[6];
  const float* be1 = (const float*)d_in[7];
  const float* g2  = (const float*)d_in[8];
  const float* be2 = (const float*)d_in[9];
  const float* g3  = (const float*)d_in[10];
  const float* be3 = (const float*)d_in[11];
  const float* g4  = (const float*)d_in[12];
  const float* be4 = (const float*)d_in[13];
  const float* Wih = (const float*)d_in[14];
  const float* Whh = (const float*)d_in[15];
  const float* bih = (const float*)d_in[16];
  const float* bhh = (const float*)d_in[17];
  const float* lw1 = (const float*)d_in[18];
  const float* lb1 = (const float*)d_in[19];
  const float* lw2 = (const float*)d_in[20];
  const float* lb2 = (const float*)d_in[21];
  const float* lw3 = (const float*)d_in[22];
  const float* lb3 = (const float*)d_in[23];
  float* out = (float*)d_out;

  // workspace layout (floats) -- st and cnt adjacent so one memset zeroes both
  float* bufA = (float*)d_ws;            // 5,000,000
  float* bufB = bufA + 5000000;          // 5,000,000
  float* bufC = bufB + 5000000;          // 5,000,000
  float* st   = bufC + 5000000;          // 8 x 128 stats (sums/sqs x4)
  int*   cnt  = (int*)(st + 8*128);      // 50,000   <- zeroed with st
  int*   cur  = cnt + NN;                // 50,000 (seeded by k_off)
  int*   off  = cur + NN;                // 50,001
  int*   part = off + NN + 1;            // 1,024 block partials
  int*   bbase= part + 1024;             // 1,024 block bases
  float* dinv = (float*)(bbase + 1024);  // 50,000
  unsigned short* ssrc = (unsigned short*)(dinv + NN);  // 800,000 u16 = 1.6 MB
  _Float16* wh = (_Float16*)(ssrc + NE); // fp16 weight images
  _Float16* w1t  = wh;            // [112][128]
  _Float16* w2t  = wh + 14336;    // [112][128]
  _Float16* wihh = wh + 28672;    // [64][128]
  _Float16* l1h  = wh + 36864;    // [64][64]
  _Float16* l2h  = wh + 40960;    // [32][64]
  float*    l3f  = (float*)(wh + 43008); // [30][32] fp32

  __half* xwh = (__half*)bufA;           // 5M halves = 10 MB staging (inside bufA)

  float* sums1 = st + 0*128; float* sqs1 = st + 1*128;
  float* sums2 = st + 2*128; float* sqs2 = st + 3*128;
  float* sums3 = st + 4*128; float* sqs3 = st + 5*128;
  float* sums4 = st + 6*128; float* sqs4 = st + 7*128;

  const int B = 256;
  const float invN = 1.0f / (float)NN;
  const int statsGrid = 784;
  const int gt = cdiv(NN, 64);           // 782 tile-blocks

  // zero stats + cnt in one shot (adjacent)
  hipMemsetAsync(st, 0, 8*128*sizeof(float) + NN*sizeof(int), stream);

  // ---- weight prep + dense-CSR build (parallel two-level scan) ----
  k_trh<<<cdiv(43968,B), B, 0, stream>>>(W1, W2, Wih, lw1, lw2, lw3,
                                         w1t, w2t, wihh, l1h, l2h, l3f);
  k_count<<<cdiv(NE,B), B, 0, stream>>>(ei + NE, cnt, NE);
  k_part <<<gt, 64, 0, stream>>>(cnt, part, NN);
  k_scan1<<<1, 1024, 0, stream>>>(part, bbase, gt);
  k_off  <<<gt, 64, 0, stream>>>(cnt, bbase, off, cur, dinv, NN, NE);
  k_scatter<<<cdiv(NE,B), B, 0, stream>>>(ei, cur, ssrc, NE);

  // ---- GCN conv 1: xws = (x @ W1)*dinv (fp16, MFMA) ; aggregate (+b1) ----
  k_mfma<100,4,7,100,0,0,0,1><<<gt, 256, 0, stream>>>(x, w1t, nullptr, nullptr,
      nullptr, nullptr, nullptr, nullptr, dinv, xwh, NN, invN);
  k_gather<<<NN, 128, 0, stream>>>(xwh, ssrc, off, dinv, b1, bufB);
  k_bn_stats<<<statsGrid, 128, 0, stream>>>(bufB, sums1, sqs1, NN, 100);

  // ---- GCN conv 2: xws = (relu(BN1(h1)) @ W2)*dinv (MFMA) ; aggregate (+b2) ----
  k_mfma<100,4,7,100,1,1,0,1><<<gt, 256, 0, stream>>>(bufB, w2t, nullptr, nullptr,
      sums1, sqs1, g1, be1, dinv, xwh, NN, invN);
  k_gather<<<NN, 128, 0, stream>>>(xwh, ssrc, off, dinv, b2, bufC);
  k_bn_stats<<<statsGrid, 128, 0, stream>>>(bufC, sums2, sqs2, NN, 100);

  // ---- u = BN2(h2) @ Wih^T + bih + bhh (MFMA) ; parallel-chunk RNN ----
  k_mfma<100,4,4,50,1,0,2,0><<<gt, 256, 0, stream>>>(bufC, wihh, bih, bhh,
      sums2, sqs2, g2, be2, nullptr, bufA, NN, invN);
  {
    const int L = 32, W = 48;
    k_rnn_par<<<cdiv(NN,L), 64, 0, stream>>>(bufA, Whh, bufB, NN, L, W);
  }

  // ---- Linear1 (MFMA) ----
  k_mfma<50,2,4,50,0,0,1,0><<<gt, 256, 0, stream>>>(bufB, l1h, lb1, nullptr,
      nullptr, nullptr, nullptr, nullptr, nullptr, bufC, NN, invN);
  k_bn_stats<<<statsGrid, 64, 0, stream>>>(bufC, sums3, sqs3, NN, 50);

  // ---- Linear2 (BN3+relu in, MFMA) ----
  k_mfma<50,2,2,30,1,1,1,0><<<gt, 256, 0, stream>>>(bufC, l2h, lb2, nullptr,
      sums3, sqs3, g3, be3, nullptr, bufA, NN, invN);
  k_bn_stats<<<statsGrid, 64, 0, stream>>>(bufA, sums4, sqs4, NN, 30);

  // ---- Linear3 (BN4+relu in) + log_softmax ----
  k_tgemm_lsm<30,30,32,32><<<gt, 64, 0, stream>>>(bufA, l3f, lb3,
      sums4, sqs4, g4, be4, out, NN, invN);
}